// Round 7
// baseline (195.528 us; speedup 1.0000x reference)
//
#include <hip/hip_runtime.h>

#define RSQRT_D 0.08838834764831843f

// =====================================================================
// kAB: blocks 0..511  -> map/polyline encoder (one block per (b,m))
//      blocks 512..767 -> agent MLP, 256 thr = 2 halves x 4 rows (8 rows/block)
// (unchanged from round 4 — verified at absmax 0.00098)
// =====================================================================
__global__ __launch_bounds__(256) void kAB_front(
    const float* __restrict__ poly, const float* __restrict__ pmask,
    const int* __restrict__ ptype, const int* __restrict__ ptl, const int* __restrict__ proute,
    const float* __restrict__ pm_w1, const float* __restrict__ pm_b1,
    const float* __restrict__ pm_w2, const float* __restrict__ pm_b2,
    const float* __restrict__ type_emb, const float* __restrict__ tl_emb, const float* __restrict__ route_emb,
    const float* __restrict__ mo_w1, const float* __restrict__ mo_b1,
    const float* __restrict__ mo_w2, const float* __restrict__ mo_b2,
    const float* __restrict__ astate, const float* __restrict__ amask,
    const float* __restrict__ ae_w1, const float* __restrict__ ae_b1,
    const float* __restrict__ ae_w2, const float* __restrict__ ae_b2,
    const float* __restrict__ ae_w3, const float* __restrict__ ae_b3,
    float* __restrict__ map_node, float* __restrict__ map_nodeT, float* __restrict__ center,
    float* __restrict__ a_emb, float* __restrict__ aT, float* __restrict__ posT)
{
    int tid = threadIdx.x;
    if (blockIdx.x < 512) {
        // ---------------- map/polyline encoder ----------------
        int bm = blockIdx.x;
        int b = bm >> 8, m = bm & 255;
        int h = tid & 127, rw = tid >> 7;
        __shared__ float xch[2][128];              // reused as mo partial buffer
        __shared__ __align__(16) float hvs[128];
        __shared__ __align__(16) float g2[128];
        __shared__ __align__(16) float h1s[2][128][12];

        // phase 1: layer-1, each (k,half) computed exactly once
        {
            int k = h;
            int half = rw;
            const float* pp = poly + bm*40 + half*20;
            float wx = pm_w1[k], wy = pm_w1[128+k], bb = pm_b1[k];
            float h1v[10];
            #pragma unroll
            for (int u = 0; u < 10; ++u) {
                float x = pp[2*u], y = pp[2*u+1];
                h1v[u] = fmaxf(fmaf(wx, x, fmaf(wy, y, bb)), 0.f);
            }
            float4 s0 = make_float4(h1v[0], h1v[1], h1v[2], h1v[3]);
            float4 s1 = make_float4(h1v[4], h1v[5], h1v[6], h1v[7]);
            float2 s2 = make_float2(h1v[8], h1v[9]);
            *(float4*)&h1s[half][k][0] = s0;
            *(float4*)&h1s[half][k][4] = s1;
            *(float2*)&h1s[half][k][8] = s2;
        }
        __syncthreads();

        // phase 2: layer-2 + max over points (k order unchanged -> bit-exact)
        float acc[10];
        #pragma unroll
        for (int u = 0; u < 10; ++u) acc[u] = 0.f;
        const float* w2p = pm_w2 + h;
        #pragma unroll 2
        for (int k = 0; k < 128; ++k) {
            float w2v = w2p[k*128];
            float4 A  = *(const float4*)&h1s[rw][k][0];
            float4 Bv = *(const float4*)&h1s[rw][k][4];
            float2 Cv = *(const float2*)&h1s[rw][k][8];
            acc[0] = fmaf(A.x,  w2v, acc[0]);
            acc[1] = fmaf(A.y,  w2v, acc[1]);
            acc[2] = fmaf(A.z,  w2v, acc[2]);
            acc[3] = fmaf(A.w,  w2v, acc[3]);
            acc[4] = fmaf(Bv.x, w2v, acc[4]);
            acc[5] = fmaf(Bv.y, w2v, acc[5]);
            acc[6] = fmaf(Bv.z, w2v, acc[6]);
            acc[7] = fmaf(Bv.w, w2v, acc[7]);
            acc[8] = fmaf(Cv.x, w2v, acc[8]);
            acc[9] = fmaf(Cv.y, w2v, acc[9]);
        }
        float mx = acc[0];
        #pragma unroll
        for (int u = 1; u < 10; ++u) mx = fmaxf(mx, acc[u]);
        xch[rw][h] = mx;
        __syncthreads();
        if (rw == 0) {
            float v = fmaxf(fmaxf(mx, xch[1][h]) + pm_b2[h], 0.f);
            int ti = min(max(ptype[bm],0),3);
            int si = min(max(ptl[bm],0),7);
            int ri = min(max(proute[bm],0),1);
            hvs[h] = v + type_emb[ti*128+h] + tl_emb[si*128+h] + route_emb[ri*128+h];
        }
        __syncthreads();
        // mo layer 1: split-k across halves (rw = k-half)
        {
            float a1 = (rw == 0) ? mo_b1[h] : 0.f;
            int k0 = rw * 64;
            for (int kc = 0; kc < 16; ++kc) {
                float4 xv = *(const float4*)&hvs[k0 + kc*4];
                a1 = fmaf(xv.x, mo_w1[(k0+kc*4+0)*128+h],
                     fmaf(xv.y, mo_w1[(k0+kc*4+1)*128+h],
                     fmaf(xv.z, mo_w1[(k0+kc*4+2)*128+h],
                     fmaf(xv.w, mo_w1[(k0+kc*4+3)*128+h], a1))));
            }
            xch[rw][h] = a1;
        }
        __syncthreads();
        if (tid < 128) g2[tid] = fmaxf(xch[0][tid] + xch[1][tid], 0.f);
        __syncthreads();
        // mo layer 2: split-k across halves
        {
            float a2 = (rw == 0) ? mo_b2[h] : 0.f;
            int k0 = rw * 64;
            for (int kc = 0; kc < 16; ++kc) {
                float4 xv = *(const float4*)&g2[k0 + kc*4];
                a2 = fmaf(xv.x, mo_w2[(k0+kc*4+0)*128+h],
                     fmaf(xv.y, mo_w2[(k0+kc*4+1)*128+h],
                     fmaf(xv.z, mo_w2[(k0+kc*4+2)*128+h],
                     fmaf(xv.w, mo_w2[(k0+kc*4+3)*128+h], a2))));
            }
            xch[rw][h] = a2;
        }
        __syncthreads();
        if (tid < 128) {
            float a2 = xch[0][tid] + xch[1][tid];
            float mk = (pmask[bm] > 0.5f) ? 1.f : 0.f;
            a2 *= mk;
            map_node[bm*128 + tid] = a2;
            map_nodeT[(b*128+tid)*256 + m] = a2;
        }
        if (tid == 0) {
            float sx = 0.f, sy = 0.f;
            #pragma unroll
            for (int l = 0; l < 20; ++l) { sx += poly[bm*40 + 2*l]; sy += poly[bm*40 + 2*l + 1]; }
            center[bm*2+0] = sx * 0.05f;
            center[bm*2+1] = sy * 0.05f;
        }
    } else {
        // ---------------- agent MLP: 2 halves x 4 rows (unchanged) ----------------
        int h = tid & 127, rp = tid >> 7;
        int r0 = (blockIdx.x - 512)*8 + rp*4;
        __shared__ float f5[2][4][5];
        __shared__ __align__(16) float a1s[2][4][128];
        if (h < 20) f5[rp][h/5][h%5] = astate[(r0 + h/5)*5 + (h%5)];
        __syncthreads();
        float b1v = ae_b1[h];
        float v[4];
        {
            float w0 = ae_w1[h], w1 = ae_w1[128+h], w2 = ae_w1[256+h], w3 = ae_w1[384+h], w4 = ae_w1[512+h];
            #pragma unroll
            for (int r = 0; r < 4; ++r) {
                float a = b1v;
                a = fmaf(f5[rp][r][0], w0, a); a = fmaf(f5[rp][r][1], w1, a);
                a = fmaf(f5[rp][r][2], w2, a); a = fmaf(f5[rp][r][3], w3, a);
                a = fmaf(f5[rp][r][4], w4, a);
                v[r] = fmaxf(a, 0.f);
            }
        }
        #pragma unroll
        for (int r = 0; r < 4; ++r) a1s[rp][r][h] = v[r];
        __syncthreads();
        {
            float b2v = ae_b2[h];
            float a0 = b2v, a1 = b2v, a2 = b2v, a3 = b2v;
            for (int kc = 0; kc < 32; ++kc) {
                float4 x0 = *(const float4*)&a1s[rp][0][kc*4];
                float4 x1 = *(const float4*)&a1s[rp][1][kc*4];
                float4 x2 = *(const float4*)&a1s[rp][2][kc*4];
                float4 x3 = *(const float4*)&a1s[rp][3][kc*4];
                float w0 = ae_w2[(kc*4+0)*128+h], w1 = ae_w2[(kc*4+1)*128+h];
                float w2 = ae_w2[(kc*4+2)*128+h], w3 = ae_w2[(kc*4+3)*128+h];
                a0 = fmaf(x0.x,w0,fmaf(x0.y,w1,fmaf(x0.z,w2,fmaf(x0.w,w3,a0))));
                a1 = fmaf(x1.x,w0,fmaf(x1.y,w1,fmaf(x1.z,w2,fmaf(x1.w,w3,a1))));
                a2 = fmaf(x2.x,w0,fmaf(x2.y,w1,fmaf(x2.z,w2,fmaf(x2.w,w3,a2))));
                a3 = fmaf(x3.x,w0,fmaf(x3.y,w1,fmaf(x3.z,w2,fmaf(x3.w,w3,a3))));
            }
            v[0]=fmaxf(a0,0.f); v[1]=fmaxf(a1,0.f); v[2]=fmaxf(a2,0.f); v[3]=fmaxf(a3,0.f);
        }
        __syncthreads();
        #pragma unroll
        for (int r = 0; r < 4; ++r) a1s[rp][r][h] = v[r];
        __syncthreads();
        {
            float b3v = ae_b3[h];
            float a0 = b3v, a1 = b3v, a2 = b3v, a3 = b3v;
            for (int kc = 0; kc < 32; ++kc) {
                float4 x0 = *(const float4*)&a1s[rp][0][kc*4];
                float4 x1 = *(const float4*)&a1s[rp][1][kc*4];
                float4 x2 = *(const float4*)&a1s[rp][2][kc*4];
                float4 x3 = *(const float4*)&a1s[rp][3][kc*4];
                float w0 = ae_w3[(kc*4+0)*128+h], w1 = ae_w3[(kc*4+1)*128+h];
                float w2 = ae_w3[(kc*4+2)*128+h], w3 = ae_w3[(kc*4+3)*128+h];
                a0 = fmaf(x0.x,w0,fmaf(x0.y,w1,fmaf(x0.z,w2,fmaf(x0.w,w3,a0))));
                a1 = fmaf(x1.x,w0,fmaf(x1.y,w1,fmaf(x1.z,w2,fmaf(x1.w,w3,a1))));
                a2 = fmaf(x2.x,w0,fmaf(x2.y,w1,fmaf(x2.z,w2,fmaf(x2.w,w3,a2))));
                a3 = fmaf(x3.x,w0,fmaf(x3.y,w1,fmaf(x3.z,w2,fmaf(x3.w,w3,a3))));
            }
            v[0]=a0; v[1]=a1; v[2]=a2; v[3]=a3;
        }
        #pragma unroll
        for (int r = 0; r < 4; ++r) {
            int rr = r0 + r;
            float mk = (amask[rr] > 0.5f) ? 1.f : 0.f;
            float e = v[r] * mk;
            a_emb[rr*128 + h] = e;
            int bb = rr >> 10, nn = (rr >> 5) & 31, tt = rr & 31;
            int bt = bb*32 + tt;
            aT[(bt*128 + h)*32 + nn] = e;
        }
        if (h < 20) {
            int r = h / 5, c = h % 5;
            int rr = r0 + r;
            int bb = rr >> 10, nn = (rr >> 5) & 31, tt = rr & 31;
            int bt = bb*32 + tt;
            float val;
            if      (c == 0) val = f5[rp][r][0];
            else if (c == 1) val = f5[rp][r][1];
            else if (c == 2) val = f5[rp][r][3];
            else if (c == 3) val = f5[rp][r][4];
            else             val = amask[rr];
            posT[(bt*5 + c)*32 + nn] = val;
        }
    }
}

// =====================================================================
// kCD_fused v7: 512 blocks x 512 thr, 4 rows/block (r0 = 4*blockIdx).
// = round-4 kernel with seg1-3 rebalanced:
//   seg1: ALL 512 threads = (m, kh) split-k map-logit partials, 4 rows,
//         64 iters each (r4: 256 threads x 128 iters while 256 idle-ish).
//   seg2: thr 0-255 combine partials -> lg4 + tau[0:128] copy
//         || thr 256-511 neighbor softmax (r4 ran this in seg1).
//   seg3: map softmax (thr 0-255) — unchanged math.
// Split-k combine association identical to round-5's verified kernel;
// all other segments bit-identical to round 4 (absmax 0.00098).
// =====================================================================
__global__ __launch_bounds__(512) void kCD_fused(
    const float* __restrict__ astate, const float* __restrict__ amask,
    const float* __restrict__ pmask,
    const float* __restrict__ a_emb, const float* __restrict__ map_node,
    const float* __restrict__ map_nodeT, const float* __restrict__ center,
    const float* __restrict__ mr_w1, const float* __restrict__ mr_b1,
    const float* __restrict__ mr_w2, const float* __restrict__ mr_b2,
    const float* __restrict__ aT, const float* __restrict__ posT,
    const float* __restrict__ nr_w1, const float* __restrict__ nr_b1,
    const float* __restrict__ nr_w2, const float* __restrict__ nr_b2,
    const float* __restrict__ to_w1, const float* __restrict__ to_b1,
    const float* __restrict__ to_w2, const float* __restrict__ to_b2,
    float* __restrict__ out)
{
    int tid = threadIdx.x;
    int r0 = blockIdx.x * 4;
    int b = r0 >> 10, t0 = r0 & 31;

    __shared__ float sp[4][256];
    __shared__ float dp[4][256];
    __shared__ float lg4[4][256];
    __shared__ __align__(16) float p4[256*4];
    __shared__ float ctxp[4][128];
    __shared__ float pj[4][32];
    __shared__ __align__(16) float tau[4][384];
    __shared__ float redn[4][128];
    __shared__ __align__(16) float gpart[4][4][128];
    __shared__ __align__(16) float g1s[4][128];

    // ---- seg1: ALL 512 threads = (m, kh), 4-row partials over 64 hh ----
    float sA[4], dt[4];
    {
        int m = tid & 255, kh = tid >> 8;
        float b2c = mr_b2[0];
        float cx = center[(b*256+m)*2+0], cy = center[(b*256+m)*2+1];
        float rx[4], ry[4], dd[4];
        #pragma unroll
        for (int r = 0; r < 4; ++r) {
            float px = astate[(r0+r)*5+0], py = astate[(r0+r)*5+1];
            rx[r] = cx - px; ry[r] = cy - py;
            dd[r] = sqrtf(rx[r]*rx[r] + ry[r]*ry[r]);
            sA[r] = kh ? 0.f : b2c;
            dt[r] = 0.f;
        }
        const float* mT = map_nodeT + b*128*256 + m;
        const float* ae = a_emb + (size_t)r0*128;
        int h0 = kh*64;
        #pragma unroll 4
        for (int q = 0; q < 64; ++q) {
            int hh = h0 + q;
            float wa = mr_w1[hh], wb = mr_w1[128+hh], wc = mr_w1[256+hh];
            float bb = mr_b1[hh], w2 = mr_w2[hh];
            float v = mT[hh*256];
            #pragma unroll
            for (int r = 0; r < 4; ++r) {
                float t1 = fmaf(rx[r], wa, fmaf(ry[r], wb, fmaf(dd[r], wc, bb)));
                sA[r] = fmaf(fmaxf(t1, 0.f), w2, sA[r]);
                dt[r] = fmaf(v, ae[r*128 + hh], dt[r]);
            }
        }
        if (kh) {
            #pragma unroll
            for (int r = 0; r < 4; ++r) { sp[r][m] = sA[r]; dp[r][m] = dt[r]; }
        }
    }
    __syncthreads();

    // ---- seg2: thr 0-255 combine -> lg4 + tau copy || thr 256-511 nbr softmax ----
    if (tid < 256) {
        int m = tid;
        bool mk = pmask[b*256+m] > 0.5f;
        #pragma unroll
        for (int r = 0; r < 4; ++r)
            lg4[r][m] = mk ? fmaf(dt[r] + dp[r][m], RSQRT_D, sA[r] + sp[r][m]) : -1e30f;
        int d = tid & 127, rq = tid >> 7;   // rq 0..1
        tau[rq][d]   = a_emb[(size_t)(r0+rq)*128 + d];
        tau[rq+2][d] = a_emb[(size_t)(r0+rq+2)*128 + d];
    } else {
        int lam = tid & 63, wv = (tid >> 6) & 3;
        int r = r0 + wv;
        int ii = (r >> 5) & 31, tt = r & 31;
        int bt = b*32 + tt;
        int j = lam & 31, hs = lam >> 5;
        float pxi = astate[r*5+0], pyi = astate[r*5+1], vxi = astate[r*5+3], vyi = astate[r*5+4];
        const float* pT = posT + bt*160;
        float pxj = pT[j], pyj = pT[32+j], vxj = pT[64+j], vyj = pT[96+j], mj = pT[128+j];
        float rpx = pxj-pxi, rpy = pyj-pyi, rvx = vxj-vxi, rvy = vyj-vyi;
        float ddv = sqrtf(rpx*rpx + rpy*rpy);
        const float* ei = a_emb + (size_t)r*128;
        const float* aTp = aT + (size_t)bt*4096 + j;
        float s = 0.f, dot = 0.f;
        int h0 = hs*64;
        #pragma unroll 8
        for (int q = 0; q < 64; ++q) {
            int hh = h0 + q;
            float wA = nr_w1[hh], wB = nr_w1[128+hh], wC = nr_w1[256+hh];
            float wD = nr_w1[384+hh], wE = nr_w1[512+hh];
            float bb = nr_b1[hh], w2 = nr_w2[hh];
            float t1 = fmaf(rpx, wA, fmaf(rpy, wB, fmaf(rvx, wC,
                       fmaf(rvy, wD, fmaf(ddv, wE, bb)))));
            s = fmaf(fmaxf(t1, 0.f), w2, s);
            dot = fmaf(ei[hh], aTp[hh*32], dot);
        }
        s   += __shfl_xor(s, 32);
        dot += __shfl_xor(dot, 32);
        bool vi = amask[r] > 0.5f, vj = mj > 0.5f;
        bool ok = vi && vj && (ddv <= 30.0f) && (j != ii);
        float lg = ok ? fmaf(dot, RSQRT_D, s + nr_b2[0]) : -1e30f;
        float mxv = lg;
        #pragma unroll
        for (int off = 16; off; off >>= 1) mxv = fmaxf(mxv, __shfl_xor(mxv, off));
        float e = (lg > -1e29f) ? expf(lg - mxv) : 0.f;
        float sm = e;
        #pragma unroll
        for (int off = 16; off; off >>= 1) sm += __shfl_xor(sm, off);
        if (hs == 0) pj[wv][j] = e / fmaxf(sm, 1e-9f);
    }
    __syncthreads();

    // ---- seg3: map softmax (thr 0-255) ----
    if (tid < 256) {
        int lam = tid & 63, wv = tid >> 6;
        float x0 = lg4[wv][lam], x1 = lg4[wv][64+lam], x2 = lg4[wv][128+lam], x3 = lg4[wv][192+lam];
        float mxv = fmaxf(fmaxf(x0,x1), fmaxf(x2,x3));
        #pragma unroll
        for (int off = 32; off; off >>= 1) mxv = fmaxf(mxv, __shfl_xor(mxv, off));
        float e0 = (x0 > -1e29f) ? expf(x0-mxv) : 0.f;
        float e1 = (x1 > -1e29f) ? expf(x1-mxv) : 0.f;
        float e2 = (x2 > -1e29f) ? expf(x2-mxv) : 0.f;
        float e3 = (x3 > -1e29f) ? expf(x3-mxv) : 0.f;
        float sm = e0+e1+e2+e3;
        #pragma unroll
        for (int off = 32; off; off >>= 1) sm += __shfl_xor(sm, off);
        float inv = 1.f / fmaxf(sm, 1e-9f);
        p4[lam*4 + wv]       = e0*inv;
        p4[(64+lam)*4 + wv]  = e1*inv;
        p4[(128+lam)*4 + wv] = e2*inv;
        p4[(192+lam)*4 + wv] = e3*inv;
    }
    __syncthreads();

    // ---- seg4: thr 0-255 PV || thr 256-511 neighbor ctx (r4-exact) ----
    float pv0 = 0.f, pv1 = 0.f, pv2 = 0.f, pv3 = 0.f;
    float na0 = 0.f, na1 = 0.f, na2 = 0.f, na3 = 0.f;
    if (tid < 256) {
        int d = tid & 127, hf = tid >> 7;
        const float* mn = map_node + (b*256 + hf*128)*128 + d;
        const float4* ppv = (const float4*)p4 + hf*128;
        #pragma unroll 4
        for (int mm = 0; mm < 128; ++mm) {
            float4 pvv = ppv[mm];
            float v = mn[mm*128];
            pv0 = fmaf(pvv.x, v, pv0); pv1 = fmaf(pvv.y, v, pv1);
            pv2 = fmaf(pvv.z, v, pv2); pv3 = fmaf(pvv.w, v, pv3);
        }
        if (hf == 1) { ctxp[0][d]=pv0; ctxp[1][d]=pv1; ctxp[2][d]=pv2; ctxp[3][d]=pv3; }
    } else {
        int local = tid - 256;
        int d = local & 127, hf = local >> 7;
        for (int jj = 0; jj < 16; ++jj) {
            int j2 = hf*16 + jj;
            float p0 = pj[0][j2], p1 = pj[1][j2], p2 = pj[2][j2], p3 = pj[3][j2];
            const float* ejb = a_emb + (size_t)((b*32 + j2)*32 + t0)*128 + d;
            na0 = fmaf(p0, ejb[0],   na0);
            na1 = fmaf(p1, ejb[128], na1);
            na2 = fmaf(p2, ejb[256], na2);
            na3 = fmaf(p3, ejb[384], na3);
        }
        if (hf == 1) { redn[0][d]=na0; redn[1][d]=na1; redn[2][d]=na2; redn[3][d]=na3; }
    }
    __syncthreads();

    // ---- seg5: combine partials into tau (r4-exact) ----
    if (tid < 128) {
        int d = tid;
        tau[0][128+d] = pv0 + ctxp[0][d];
        tau[1][128+d] = pv1 + ctxp[1][d];
        tau[2][128+d] = pv2 + ctxp[2][d];
        tau[3][128+d] = pv3 + ctxp[3][d];
    } else if (tid >= 256 && tid < 384) {
        int d = tid - 256;
        tau[0][256+d] = na0 + redn[0][d];
        tau[1][256+d] = na1 + redn[1][d];
        tau[2][256+d] = na2 + redn[2][d];
        tau[3][256+d] = na3 + redn[3][d];
    }
    __syncthreads();

    // ---- seg6: to_w1 MLP (r4-exact: col-split across halves, kq x 24) ----
    {
        int h6 = tid & 63, kq = (tid >> 6) & 3, side = tid >> 8;
        int col = side*64 + h6;
        float a0v = 0.f, a1v = 0.f, a2v = 0.f, a3v = 0.f;
        for (int c = 0; c < 24; ++c) {
            int k4 = kq*24 + c;
            float4 x0 = *(const float4*)&tau[0][k4*4];
            float4 x1 = *(const float4*)&tau[1][k4*4];
            float4 x2 = *(const float4*)&tau[2][k4*4];
            float4 x3 = *(const float4*)&tau[3][k4*4];
            float w0 = to_w1[(k4*4+0)*128 + col];
            float w1 = to_w1[(k4*4+1)*128 + col];
            float w2 = to_w1[(k4*4+2)*128 + col];
            float w3 = to_w1[(k4*4+3)*128 + col];
            a0v = fmaf(x0.x,w0,fmaf(x0.y,w1,fmaf(x0.z,w2,fmaf(x0.w,w3,a0v))));
            a1v = fmaf(x1.x,w0,fmaf(x1.y,w1,fmaf(x1.z,w2,fmaf(x1.w,w3,a1v))));
            a2v = fmaf(x2.x,w0,fmaf(x2.y,w1,fmaf(x2.z,w2,fmaf(x2.w,w3,a2v))));
            a3v = fmaf(x3.x,w0,fmaf(x3.y,w1,fmaf(x3.z,w2,fmaf(x3.w,w3,a3v))));
        }
        gpart[kq][0][col] = a0v;
        gpart[kq][1][col] = a1v;
        gpart[kq][2][col] = a2v;
        gpart[kq][3][col] = a3v;
    }
    __syncthreads();

    // ---- seg7: g1s = relu(sum of 4 partials + bias), 512 thr = 128 h x 4 rows ----
    {
        int h = tid & 127, rr = tid >> 7;
        float s = gpart[0][rr][h] + gpart[1][rr][h] + gpart[2][rr][h] + gpart[3][rr][h];
        g1s[rr][h] = fmaxf(s + to_b1[h], 0.f);
    }
    __syncthreads();

    // ---- seg8: output MLP (thr 0-255 = 64 o x 4 rows, r4-exact) ----
    if (tid < 256) {
        int o = tid & 63, row = tid >> 6;
        float a2 = to_b2[o];
        for (int kc = 0; kc < 32; ++kc) {
            float4 g = *(const float4*)&g1s[row][kc*4];
            a2 = fmaf(g.x, to_w2[(kc*4+0)*64 + o],
                 fmaf(g.y, to_w2[(kc*4+1)*64 + o],
                 fmaf(g.z, to_w2[(kc*4+2)*64 + o],
                 fmaf(g.w, to_w2[(kc*4+3)*64 + o], a2))));
        }
        float mk = (amask[r0+row] > 0.5f) ? 1.f : 0.f;
        out[(r0+row)*64 + o] = a2 * mk;
    }
}

extern "C" void kernel_launch(void* const* d_in, const int* in_sizes, int n_in,
                              void* d_out, int out_size, void* d_ws, size_t ws_size,
                              hipStream_t stream) {
    const float* agents_state  = (const float*)d_in[0];
    const float* agents_mask   = (const float*)d_in[1];
    const float* map_polylines = (const float*)d_in[2];
    const float* map_poly_mask = (const float*)d_in[3];
    const int*   map_poly_type = (const int*)d_in[4];
    const int*   map_tl_status = (const int*)d_in[5];
    const int*   map_on_route  = (const int*)d_in[6];
    const float* pm_w1 = (const float*)d_in[7];
    const float* pm_b1 = (const float*)d_in[8];
    const float* pm_w2 = (const float*)d_in[9];
    const float* pm_b2 = (const float*)d_in[10];
    const float* type_emb  = (const float*)d_in[11];
    const float* tl_emb    = (const float*)d_in[12];
    const float* route_emb = (const float*)d_in[13];
    const float* mo_w1 = (const float*)d_in[14];
    const float* mo_b1 = (const float*)d_in[15];
    const float* mo_w2 = (const float*)d_in[16];
    const float* mo_b2 = (const float*)d_in[17];
    const float* ae_w1 = (const float*)d_in[18];
    const float* ae_b1 = (const float*)d_in[19];
    const float* ae_w2 = (const float*)d_in[20];
    const float* ae_b2 = (const float*)d_in[21];
    const float* ae_w3 = (const float*)d_in[22];
    const float* ae_b3 = (const float*)d_in[23];
    const float* mr_w1 = (const float*)d_in[24];
    const float* mr_b1 = (const float*)d_in[25];
    const float* mr_w2 = (const float*)d_in[26];
    const float* mr_b2 = (const float*)d_in[27];
    const float* nr_w1 = (const float*)d_in[28];
    const float* nr_b1 = (const float*)d_in[29];
    const float* nr_w2 = (const float*)d_in[30];
    const float* nr_b2 = (const float*)d_in[31];
    const float* to_w1 = (const float*)d_in[32];
    const float* to_b1 = (const float*)d_in[33];
    const float* to_w2 = (const float*)d_in[34];
    const float* to_b2 = (const float*)d_in[35];

    float* ws = (float*)d_ws;
    float* map_node  = ws;                 // 65536
    float* map_nodeT = ws + 65536;         // 65536
    float* center    = ws + 131072;        // 1024
    float* a_emb     = ws + 132096;        // 262144
    float* aT        = ws + 394240;        // 262144
    float* posT      = ws + 656384;        // 10240
    // map_ctx / p_n live entirely in LDS inside kCD_fused

    float* out = (float*)d_out;

    kAB_front<<<768, 256, 0, stream>>>(map_polylines, map_poly_mask,
        map_poly_type, map_tl_status, map_on_route,
        pm_w1, pm_b1, pm_w2, pm_b2, type_emb, tl_emb, route_emb,
        mo_w1, mo_b1, mo_w2, mo_b2,
        agents_state, agents_mask,
        ae_w1, ae_b1, ae_w2, ae_b2, ae_w3, ae_b3,
        map_node, map_nodeT, center, a_emb, aT, posT);

    kCD_fused<<<512, 512, 0, stream>>>(agents_state, agents_mask, map_poly_mask,
        a_emb, map_node, map_nodeT, center,
        mr_w1, mr_b1, mr_w2, mr_b2,
        aT, posT,
        nr_w1, nr_b1, nr_w2, nr_b2,
        to_w1, to_b1, to_w2, to_b2,
        out);
}

// Round 8
// 177.990 us; speedup vs baseline: 1.0985x; 1.0985x over previous
//
#include <hip/hip_runtime.h>

#define RSQRT_D 0.08838834764831843f

// =====================================================================
// kAB: blocks 0..511  -> map/polyline encoder (one block per (b,m))
//      blocks 512..767 -> agent MLP, 256 thr = 2 halves x 4 rows (8 rows/block)
// (round-4 version — verified at absmax 0.00098, total 180.9 µs)
// =====================================================================
__global__ __launch_bounds__(256) void kAB_front(
    const float* __restrict__ poly, const float* __restrict__ pmask,
    const int* __restrict__ ptype, const int* __restrict__ ptl, const int* __restrict__ proute,
    const float* __restrict__ pm_w1, const float* __restrict__ pm_b1,
    const float* __restrict__ pm_w2, const float* __restrict__ pm_b2,
    const float* __restrict__ type_emb, const float* __restrict__ tl_emb, const float* __restrict__ route_emb,
    const float* __restrict__ mo_w1, const float* __restrict__ mo_b1,
    const float* __restrict__ mo_w2, const float* __restrict__ mo_b2,
    const float* __restrict__ astate, const float* __restrict__ amask,
    const float* __restrict__ ae_w1, const float* __restrict__ ae_b1,
    const float* __restrict__ ae_w2, const float* __restrict__ ae_b2,
    const float* __restrict__ ae_w3, const float* __restrict__ ae_b3,
    float* __restrict__ map_node, float* __restrict__ map_nodeT, float* __restrict__ center,
    float* __restrict__ a_emb, float* __restrict__ aT, float* __restrict__ posT)
{
    int tid = threadIdx.x;
    if (blockIdx.x < 512) {
        // ---------------- map/polyline encoder ----------------
        int bm = blockIdx.x;
        int b = bm >> 8, m = bm & 255;
        int h = tid & 127, rw = tid >> 7;
        __shared__ float xch[2][128];              // reused as mo partial buffer
        __shared__ __align__(16) float hvs[128];
        __shared__ __align__(16) float g2[128];
        __shared__ __align__(16) float h1s[2][128][12];

        // phase 1: layer-1, each (k,half) computed exactly once
        {
            int k = h;
            int half = rw;
            const float* pp = poly + bm*40 + half*20;
            float wx = pm_w1[k], wy = pm_w1[128+k], bb = pm_b1[k];
            float h1v[10];
            #pragma unroll
            for (int u = 0; u < 10; ++u) {
                float x = pp[2*u], y = pp[2*u+1];
                h1v[u] = fmaxf(fmaf(wx, x, fmaf(wy, y, bb)), 0.f);
            }
            float4 s0 = make_float4(h1v[0], h1v[1], h1v[2], h1v[3]);
            float4 s1 = make_float4(h1v[4], h1v[5], h1v[6], h1v[7]);
            float2 s2 = make_float2(h1v[8], h1v[9]);
            *(float4*)&h1s[half][k][0] = s0;
            *(float4*)&h1s[half][k][4] = s1;
            *(float2*)&h1s[half][k][8] = s2;
        }
        __syncthreads();

        // phase 2: layer-2 + max over points (k order unchanged -> bit-exact)
        float acc[10];
        #pragma unroll
        for (int u = 0; u < 10; ++u) acc[u] = 0.f;
        const float* w2p = pm_w2 + h;
        #pragma unroll 2
        for (int k = 0; k < 128; ++k) {
            float w2v = w2p[k*128];
            float4 A  = *(const float4*)&h1s[rw][k][0];
            float4 Bv = *(const float4*)&h1s[rw][k][4];
            float2 Cv = *(const float2*)&h1s[rw][k][8];
            acc[0] = fmaf(A.x,  w2v, acc[0]);
            acc[1] = fmaf(A.y,  w2v, acc[1]);
            acc[2] = fmaf(A.z,  w2v, acc[2]);
            acc[3] = fmaf(A.w,  w2v, acc[3]);
            acc[4] = fmaf(Bv.x, w2v, acc[4]);
            acc[5] = fmaf(Bv.y, w2v, acc[5]);
            acc[6] = fmaf(Bv.z, w2v, acc[6]);
            acc[7] = fmaf(Bv.w, w2v, acc[7]);
            acc[8] = fmaf(Cv.x, w2v, acc[8]);
            acc[9] = fmaf(Cv.y, w2v, acc[9]);
        }
        float mx = acc[0];
        #pragma unroll
        for (int u = 1; u < 10; ++u) mx = fmaxf(mx, acc[u]);
        xch[rw][h] = mx;
        __syncthreads();
        if (rw == 0) {
            float v = fmaxf(fmaxf(mx, xch[1][h]) + pm_b2[h], 0.f);
            int ti = min(max(ptype[bm],0),3);
            int si = min(max(ptl[bm],0),7);
            int ri = min(max(proute[bm],0),1);
            hvs[h] = v + type_emb[ti*128+h] + tl_emb[si*128+h] + route_emb[ri*128+h];
        }
        __syncthreads();
        // mo layer 1: split-k across halves (rw = k-half)
        {
            float a1 = (rw == 0) ? mo_b1[h] : 0.f;
            int k0 = rw * 64;
            for (int kc = 0; kc < 16; ++kc) {
                float4 xv = *(const float4*)&hvs[k0 + kc*4];
                a1 = fmaf(xv.x, mo_w1[(k0+kc*4+0)*128+h],
                     fmaf(xv.y, mo_w1[(k0+kc*4+1)*128+h],
                     fmaf(xv.z, mo_w1[(k0+kc*4+2)*128+h],
                     fmaf(xv.w, mo_w1[(k0+kc*4+3)*128+h], a1))));
            }
            xch[rw][h] = a1;
        }
        __syncthreads();
        if (tid < 128) g2[tid] = fmaxf(xch[0][tid] + xch[1][tid], 0.f);
        __syncthreads();
        // mo layer 2: split-k across halves
        {
            float a2 = (rw == 0) ? mo_b2[h] : 0.f;
            int k0 = rw * 64;
            for (int kc = 0; kc < 16; ++kc) {
                float4 xv = *(const float4*)&g2[k0 + kc*4];
                a2 = fmaf(xv.x, mo_w2[(k0+kc*4+0)*128+h],
                     fmaf(xv.y, mo_w2[(k0+kc*4+1)*128+h],
                     fmaf(xv.z, mo_w2[(k0+kc*4+2)*128+h],
                     fmaf(xv.w, mo_w2[(k0+kc*4+3)*128+h], a2))));
            }
            xch[rw][h] = a2;
        }
        __syncthreads();
        if (tid < 128) {
            float a2 = xch[0][tid] + xch[1][tid];
            float mk = (pmask[bm] > 0.5f) ? 1.f : 0.f;
            a2 *= mk;
            map_node[bm*128 + tid] = a2;
            map_nodeT[(b*128+tid)*256 + m] = a2;
        }
        if (tid == 0) {
            float sx = 0.f, sy = 0.f;
            #pragma unroll
            for (int l = 0; l < 20; ++l) { sx += poly[bm*40 + 2*l]; sy += poly[bm*40 + 2*l + 1]; }
            center[bm*2+0] = sx * 0.05f;
            center[bm*2+1] = sy * 0.05f;
        }
    } else {
        // ---------------- agent MLP: 2 halves x 4 rows ----------------
        int h = tid & 127, rp = tid >> 7;
        int r0 = (blockIdx.x - 512)*8 + rp*4;
        __shared__ float f5[2][4][5];
        __shared__ __align__(16) float a1s[2][4][128];
        if (h < 20) f5[rp][h/5][h%5] = astate[(r0 + h/5)*5 + (h%5)];
        __syncthreads();
        float b1v = ae_b1[h];
        float v[4];
        {
            float w0 = ae_w1[h], w1 = ae_w1[128+h], w2 = ae_w1[256+h], w3 = ae_w1[384+h], w4 = ae_w1[512+h];
            #pragma unroll
            for (int r = 0; r < 4; ++r) {
                float a = b1v;
                a = fmaf(f5[rp][r][0], w0, a); a = fmaf(f5[rp][r][1], w1, a);
                a = fmaf(f5[rp][r][2], w2, a); a = fmaf(f5[rp][r][3], w3, a);
                a = fmaf(f5[rp][r][4], w4, a);
                v[r] = fmaxf(a, 0.f);
            }
        }
        #pragma unroll
        for (int r = 0; r < 4; ++r) a1s[rp][r][h] = v[r];
        __syncthreads();
        {
            float b2v = ae_b2[h];
            float a0 = b2v, a1 = b2v, a2 = b2v, a3 = b2v;
            for (int kc = 0; kc < 32; ++kc) {
                float4 x0 = *(const float4*)&a1s[rp][0][kc*4];
                float4 x1 = *(const float4*)&a1s[rp][1][kc*4];
                float4 x2 = *(const float4*)&a1s[rp][2][kc*4];
                float4 x3 = *(const float4*)&a1s[rp][3][kc*4];
                float w0 = ae_w2[(kc*4+0)*128+h], w1 = ae_w2[(kc*4+1)*128+h];
                float w2 = ae_w2[(kc*4+2)*128+h], w3 = ae_w2[(kc*4+3)*128+h];
                a0 = fmaf(x0.x,w0,fmaf(x0.y,w1,fmaf(x0.z,w2,fmaf(x0.w,w3,a0))));
                a1 = fmaf(x1.x,w0,fmaf(x1.y,w1,fmaf(x1.z,w2,fmaf(x1.w,w3,a1))));
                a2 = fmaf(x2.x,w0,fmaf(x2.y,w1,fmaf(x2.z,w2,fmaf(x2.w,w3,a2))));
                a3 = fmaf(x3.x,w0,fmaf(x3.y,w1,fmaf(x3.z,w2,fmaf(x3.w,w3,a3))));
            }
            v[0]=fmaxf(a0,0.f); v[1]=fmaxf(a1,0.f); v[2]=fmaxf(a2,0.f); v[3]=fmaxf(a3,0.f);
        }
        __syncthreads();
        #pragma unroll
        for (int r = 0; r < 4; ++r) a1s[rp][r][h] = v[r];
        __syncthreads();
        {
            float b3v = ae_b3[h];
            float a0 = b3v, a1 = b3v, a2 = b3v, a3 = b3v;
            for (int kc = 0; kc < 32; ++kc) {
                float4 x0 = *(const float4*)&a1s[rp][0][kc*4];
                float4 x1 = *(const float4*)&a1s[rp][1][kc*4];
                float4 x2 = *(const float4*)&a1s[rp][2][kc*4];
                float4 x3 = *(const float4*)&a1s[rp][3][kc*4];
                float w0 = ae_w3[(kc*4+0)*128+h], w1 = ae_w3[(kc*4+1)*128+h];
                float w2 = ae_w3[(kc*4+2)*128+h], w3 = ae_w3[(kc*4+3)*128+h];
                a0 = fmaf(x0.x,w0,fmaf(x0.y,w1,fmaf(x0.z,w2,fmaf(x0.w,w3,a0))));
                a1 = fmaf(x1.x,w0,fmaf(x1.y,w1,fmaf(x1.z,w2,fmaf(x1.w,w3,a1))));
                a2 = fmaf(x2.x,w0,fmaf(x2.y,w1,fmaf(x2.z,w2,fmaf(x2.w,w3,a2))));
                a3 = fmaf(x3.x,w0,fmaf(x3.y,w1,fmaf(x3.z,w2,fmaf(x3.w,w3,a3))));
            }
            v[0]=a0; v[1]=a1; v[2]=a2; v[3]=a3;
        }
        #pragma unroll
        for (int r = 0; r < 4; ++r) {
            int rr = r0 + r;
            float mk = (amask[rr] > 0.5f) ? 1.f : 0.f;
            float e = v[r] * mk;
            a_emb[rr*128 + h] = e;
            int bb = rr >> 10, nn = (rr >> 5) & 31, tt = rr & 31;
            int bt = bb*32 + tt;
            aT[(bt*128 + h)*32 + nn] = e;
        }
        if (h < 20) {
            int r = h / 5, c = h % 5;
            int rr = r0 + r;
            int bb = rr >> 10, nn = (rr >> 5) & 31, tt = rr & 31;
            int bt = bb*32 + tt;
            float val;
            if      (c == 0) val = f5[rp][r][0];
            else if (c == 1) val = f5[rp][r][1];
            else if (c == 2) val = f5[rp][r][3];
            else if (c == 3) val = f5[rp][r][4];
            else             val = amask[rr];
            posT[(bt*5 + c)*32 + nn] = val;
        }
    }
}

// =====================================================================
// kCD_fused (round-4 version): 512 blocks x 512 thr, 4 rows/block.
// seg1: thr 0-255 map logits (thread=m, 4 row-accumulators; mT streamed
//       once per 4 rows) CONCURRENT with thr 256-511 neighbor softmax.
// This concurrency IS the critical-path optimum: r5 (2 rows, occupancy up),
// r6 (8 rows, traffic down), r7 (split-k serialization) all regressed.
// =====================================================================
__global__ __launch_bounds__(512) void kCD_fused(
    const float* __restrict__ astate, const float* __restrict__ amask,
    const float* __restrict__ pmask,
    const float* __restrict__ a_emb, const float* __restrict__ map_node,
    const float* __restrict__ map_nodeT, const float* __restrict__ center,
    const float* __restrict__ mr_w1, const float* __restrict__ mr_b1,
    const float* __restrict__ mr_w2, const float* __restrict__ mr_b2,
    const float* __restrict__ aT, const float* __restrict__ posT,
    const float* __restrict__ nr_w1, const float* __restrict__ nr_b1,
    const float* __restrict__ nr_w2, const float* __restrict__ nr_b2,
    const float* __restrict__ to_w1, const float* __restrict__ to_b1,
    const float* __restrict__ to_w2, const float* __restrict__ to_b2,
    float* __restrict__ out)
{
    int tid = threadIdx.x;
    int r0 = blockIdx.x * 4;
    int b = r0 >> 10, t0 = r0 & 31;

    __shared__ float lg4[4][256];
    __shared__ __align__(16) float p4[256*4];
    __shared__ float ctxp[4][128];
    __shared__ float pj[4][32];
    __shared__ __align__(16) float tau[4][384];
    __shared__ float redn[4][128];
    __shared__ __align__(16) float gpart[4][4][128];
    __shared__ __align__(16) float g1s[4][128];

    // ---- seg1: thr 0-255 map logits (thread=m, 4 rows) || thr 256-511 nbr softmax ----
    if (tid < 256) {
        int m = tid;
        float rx[4], ry[4], dd[4], dt[4], sA[4];
        float b2c = mr_b2[0];
        float cx = center[(b*256+m)*2+0], cy = center[(b*256+m)*2+1];
        #pragma unroll
        for (int r = 0; r < 4; ++r) {
            float px = astate[(r0+r)*5+0], py = astate[(r0+r)*5+1];
            rx[r] = cx - px; ry[r] = cy - py;
            dd[r] = sqrtf(rx[r]*rx[r] + ry[r]*ry[r]);
            dt[r] = 0.f; sA[r] = b2c;
        }
        const float* mT = map_nodeT + b*128*256 + m;
        const float* ae0 = a_emb + (size_t)(r0+0)*128;
        const float* ae1 = a_emb + (size_t)(r0+1)*128;
        const float* ae2 = a_emb + (size_t)(r0+2)*128;
        const float* ae3 = a_emb + (size_t)(r0+3)*128;
        #pragma unroll 4
        for (int hh = 0; hh < 128; ++hh) {
            float wa = mr_w1[hh], wb = mr_w1[128+hh], wc = mr_w1[256+hh];
            float bb = mr_b1[hh], w2 = mr_w2[hh];
            float v = mT[hh*256];
            float t10 = fmaf(rx[0], wa, fmaf(ry[0], wb, fmaf(dd[0], wc, bb)));
            float t11 = fmaf(rx[1], wa, fmaf(ry[1], wb, fmaf(dd[1], wc, bb)));
            float t12 = fmaf(rx[2], wa, fmaf(ry[2], wb, fmaf(dd[2], wc, bb)));
            float t13 = fmaf(rx[3], wa, fmaf(ry[3], wb, fmaf(dd[3], wc, bb)));
            sA[0] = fmaf(fmaxf(t10, 0.f), w2, sA[0]);
            sA[1] = fmaf(fmaxf(t11, 0.f), w2, sA[1]);
            sA[2] = fmaf(fmaxf(t12, 0.f), w2, sA[2]);
            sA[3] = fmaf(fmaxf(t13, 0.f), w2, sA[3]);
            dt[0] = fmaf(v, ae0[hh], dt[0]);
            dt[1] = fmaf(v, ae1[hh], dt[1]);
            dt[2] = fmaf(v, ae2[hh], dt[2]);
            dt[3] = fmaf(v, ae3[hh], dt[3]);
        }
        bool mk = pmask[b*256+m] > 0.5f;
        #pragma unroll
        for (int r = 0; r < 4; ++r)
            lg4[r][m] = mk ? fmaf(dt[r], RSQRT_D, sA[r]) : -1e30f;
    } else {
        int lam = tid & 63, wv = (tid >> 6) & 3;
        int r = r0 + wv;
        int ii = (r >> 5) & 31, tt = r & 31;
        int bt = b*32 + tt;
        int j = lam & 31, hs = lam >> 5;
        float pxi = astate[r*5+0], pyi = astate[r*5+1], vxi = astate[r*5+3], vyi = astate[r*5+4];
        const float* pT = posT + bt*160;
        float pxj = pT[j], pyj = pT[32+j], vxj = pT[64+j], vyj = pT[96+j], mj = pT[128+j];
        float rpx = pxj-pxi, rpy = pyj-pyi, rvx = vxj-vxi, rvy = vyj-vyi;
        float ddv = sqrtf(rpx*rpx + rpy*rpy);
        const float* ei = a_emb + (size_t)r*128;
        const float* aTp = aT + (size_t)bt*4096 + j;
        float s = 0.f, dot = 0.f;
        int h0 = hs*64;
        #pragma unroll 8
        for (int q = 0; q < 64; ++q) {
            int hh = h0 + q;
            float wA = nr_w1[hh], wB = nr_w1[128+hh], wC = nr_w1[256+hh];
            float wD = nr_w1[384+hh], wE = nr_w1[512+hh];
            float bb = nr_b1[hh], w2 = nr_w2[hh];
            float t1 = fmaf(rpx, wA, fmaf(rpy, wB, fmaf(rvx, wC,
                       fmaf(rvy, wD, fmaf(ddv, wE, bb)))));
            s = fmaf(fmaxf(t1, 0.f), w2, s);
            dot = fmaf(ei[hh], aTp[hh*32], dot);
        }
        s   += __shfl_xor(s, 32);
        dot += __shfl_xor(dot, 32);
        bool vi = amask[r] > 0.5f, vj = mj > 0.5f;
        bool ok = vi && vj && (ddv <= 30.0f) && (j != ii);
        float lg = ok ? fmaf(dot, RSQRT_D, s + nr_b2[0]) : -1e30f;
        float mxv = lg;
        #pragma unroll
        for (int off = 16; off; off >>= 1) mxv = fmaxf(mxv, __shfl_xor(mxv, off));
        float e = (lg > -1e29f) ? expf(lg - mxv) : 0.f;
        float sm = e;
        #pragma unroll
        for (int off = 16; off; off >>= 1) sm += __shfl_xor(sm, off);
        if (hs == 0) pj[wv][j] = e / fmaxf(sm, 1e-9f);
    }
    __syncthreads();

    // ---- seg2: thr 0-255 map softmax || thr 256-511 a_emb -> tau copy ----
    if (tid < 256) {
        int lam = tid & 63, wv = tid >> 6;
        float x0 = lg4[wv][lam], x1 = lg4[wv][64+lam], x2 = lg4[wv][128+lam], x3 = lg4[wv][192+lam];
        float mxv = fmaxf(fmaxf(x0,x1), fmaxf(x2,x3));
        #pragma unroll
        for (int off = 32; off; off >>= 1) mxv = fmaxf(mxv, __shfl_xor(mxv, off));
        float e0 = (x0 > -1e29f) ? expf(x0-mxv) : 0.f;
        float e1 = (x1 > -1e29f) ? expf(x1-mxv) : 0.f;
        float e2 = (x2 > -1e29f) ? expf(x2-mxv) : 0.f;
        float e3 = (x3 > -1e29f) ? expf(x3-mxv) : 0.f;
        float sm = e0+e1+e2+e3;
        #pragma unroll
        for (int off = 32; off; off >>= 1) sm += __shfl_xor(sm, off);
        float inv = 1.f / fmaxf(sm, 1e-9f);
        p4[lam*4 + wv]       = e0*inv;
        p4[(64+lam)*4 + wv]  = e1*inv;
        p4[(128+lam)*4 + wv] = e2*inv;
        p4[(192+lam)*4 + wv] = e3*inv;
    } else {
        int idx = tid - 256;
        int d = idx & 127, rr = idx >> 7;
        tau[rr][d]   = a_emb[(size_t)(r0+rr)*128 + d];
        tau[rr+2][d] = a_emb[(size_t)(r0+rr+2)*128 + d];
    }
    __syncthreads();

    // ---- seg3: thr 0-255 PV || thr 256-511 neighbor ctx ----
    float pv0 = 0.f, pv1 = 0.f, pv2 = 0.f, pv3 = 0.f;
    float na0 = 0.f, na1 = 0.f, na2 = 0.f, na3 = 0.f;
    if (tid < 256) {
        int d = tid & 127, hf = tid >> 7;
        const float* mn = map_node + (b*256 + hf*128)*128 + d;
        const float4* ppv = (const float4*)p4 + hf*128;
        #pragma unroll 4
        for (int mm = 0; mm < 128; ++mm) {
            float4 pvv = ppv[mm];
            float v = mn[mm*128];
            pv0 = fmaf(pvv.x, v, pv0); pv1 = fmaf(pvv.y, v, pv1);
            pv2 = fmaf(pvv.z, v, pv2); pv3 = fmaf(pvv.w, v, pv3);
        }
        if (hf == 1) { ctxp[0][d]=pv0; ctxp[1][d]=pv1; ctxp[2][d]=pv2; ctxp[3][d]=pv3; }
    } else {
        int local = tid - 256;
        int d = local & 127, hf = local >> 7;
        for (int jj = 0; jj < 16; ++jj) {
            int j2 = hf*16 + jj;
            float p0 = pj[0][j2], p1 = pj[1][j2], p2 = pj[2][j2], p3 = pj[3][j2];
            const float* ejb = a_emb + (size_t)((b*32 + j2)*32 + t0)*128 + d;
            na0 = fmaf(p0, ejb[0],   na0);
            na1 = fmaf(p1, ejb[128], na1);
            na2 = fmaf(p2, ejb[256], na2);
            na3 = fmaf(p3, ejb[384], na3);
        }
        if (hf == 1) { redn[0][d]=na0; redn[1][d]=na1; redn[2][d]=na2; redn[3][d]=na3; }
    }
    __syncthreads();

    // ---- seg4: combine partials into tau ----
    if (tid < 128) {
        int d = tid;
        tau[0][128+d] = pv0 + ctxp[0][d];
        tau[1][128+d] = pv1 + ctxp[1][d];
        tau[2][128+d] = pv2 + ctxp[2][d];
        tau[3][128+d] = pv3 + ctxp[3][d];
    } else if (tid >= 256 && tid < 384) {
        int d = tid - 256;
        tau[0][256+d] = na0 + redn[0][d];
        tau[1][256+d] = na1 + redn[1][d];
        tau[2][256+d] = na2 + redn[2][d];
        tau[3][256+d] = na3 + redn[3][d];
    }
    __syncthreads();

    // ---- seg5: to_w1 MLP, 512 threads: col-split across halves, kq x 24 ----
    {
        int h6 = tid & 63, kq = (tid >> 6) & 3, side = tid >> 8;
        int col = side*64 + h6;
        float a0v = 0.f, a1v = 0.f, a2v = 0.f, a3v = 0.f;
        for (int c = 0; c < 24; ++c) {
            int k4 = kq*24 + c;
            float4 x0 = *(const float4*)&tau[0][k4*4];
            float4 x1 = *(const float4*)&tau[1][k4*4];
            float4 x2 = *(const float4*)&tau[2][k4*4];
            float4 x3 = *(const float4*)&tau[3][k4*4];
            float w0 = to_w1[(k4*4+0)*128 + col];
            float w1 = to_w1[(k4*4+1)*128 + col];
            float w2 = to_w1[(k4*4+2)*128 + col];
            float w3 = to_w1[(k4*4+3)*128 + col];
            a0v = fmaf(x0.x,w0,fmaf(x0.y,w1,fmaf(x0.z,w2,fmaf(x0.w,w3,a0v))));
            a1v = fmaf(x1.x,w0,fmaf(x1.y,w1,fmaf(x1.z,w2,fmaf(x1.w,w3,a1v))));
            a2v = fmaf(x2.x,w0,fmaf(x2.y,w1,fmaf(x2.z,w2,fmaf(x2.w,w3,a2v))));
            a3v = fmaf(x3.x,w0,fmaf(x3.y,w1,fmaf(x3.z,w2,fmaf(x3.w,w3,a3v))));
        }
        gpart[kq][0][col] = a0v;
        gpart[kq][1][col] = a1v;
        gpart[kq][2][col] = a2v;
        gpart[kq][3][col] = a3v;
    }
    __syncthreads();

    // ---- seg6: g1s = relu(sum of 4 partials + bias), 512 thr = 128 h x 4 rows ----
    {
        int h = tid & 127, rr = tid >> 7;
        float s = gpart[0][rr][h] + gpart[1][rr][h] + gpart[2][rr][h] + gpart[3][rr][h];
        g1s[rr][h] = fmaxf(s + to_b1[h], 0.f);
    }
    __syncthreads();

    // ---- seg7: output MLP (thr 0-255 = 64 o x 4 rows) ----
    if (tid < 256) {
        int o = tid & 63, row = tid >> 6;
        float a2 = to_b2[o];
        for (int kc = 0; kc < 32; ++kc) {
            float4 g = *(const float4*)&g1s[row][kc*4];
            a2 = fmaf(g.x, to_w2[(kc*4+0)*64 + o],
                 fmaf(g.y, to_w2[(kc*4+1)*64 + o],
                 fmaf(g.z, to_w2[(kc*4+2)*64 + o],
                 fmaf(g.w, to_w2[(kc*4+3)*64 + o], a2))));
        }
        float mk = (amask[r0+row] > 0.5f) ? 1.f : 0.f;
        out[(r0+row)*64 + o] = a2 * mk;
    }
}

extern "C" void kernel_launch(void* const* d_in, const int* in_sizes, int n_in,
                              void* d_out, int out_size, void* d_ws, size_t ws_size,
                              hipStream_t stream) {
    const float* agents_state  = (const float*)d_in[0];
    const float* agents_mask   = (const float*)d_in[1];
    const float* map_polylines = (const float*)d_in[2];
    const float* map_poly_mask = (const float*)d_in[3];
    const int*   map_poly_type = (const int*)d_in[4];
    const int*   map_tl_status = (const int*)d_in[5];
    const int*   map_on_route  = (const int*)d_in[6];
    const float* pm_w1 = (const float*)d_in[7];
    const float* pm_b1 = (const float*)d_in[8];
    const float* pm_w2 = (const float*)d_in[9];
    const float* pm_b2 = (const float*)d_in[10];
    const float* type_emb  = (const float*)d_in[11];
    const float* tl_emb    = (const float*)d_in[12];
    const float* route_emb = (const float*)d_in[13];
    const float* mo_w1 = (const float*)d_in[14];
    const float* mo_b1 = (const float*)d_in[15];
    const float* mo_w2 = (const float*)d_in[16];
    const float* mo_b2 = (const float*)d_in[17];
    const float* ae_w1 = (const float*)d_in[18];
    const float* ae_b1 = (const float*)d_in[19];
    const float* ae_w2 = (const float*)d_in[20];
    const float* ae_b2 = (const float*)d_in[21];
    const float* ae_w3 = (const float*)d_in[22];
    const float* ae_b3 = (const float*)d_in[23];
    const float* mr_w1 = (const float*)d_in[24];
    const float* mr_b1 = (const float*)d_in[25];
    const float* mr_w2 = (const float*)d_in[26];
    const float* mr_b2 = (const float*)d_in[27];
    const float* nr_w1 = (const float*)d_in[28];
    const float* nr_b1 = (const float*)d_in[29];
    const float* nr_w2 = (const float*)d_in[30];
    const float* nr_b2 = (const float*)d_in[31];
    const float* to_w1 = (const float*)d_in[32];
    const float* to_b1 = (const float*)d_in[33];
    const float* to_w2 = (const float*)d_in[34];
    const float* to_b2 = (const float*)d_in[35];

    float* ws = (float*)d_ws;
    float* map_node  = ws;                 // 65536
    float* map_nodeT = ws + 65536;         // 65536
    float* center    = ws + 131072;        // 1024
    float* a_emb     = ws + 132096;        // 262144
    float* aT        = ws + 394240;        // 262144
    float* posT      = ws + 656384;        // 10240
    // map_ctx / p_n live entirely in LDS inside kCD_fused

    float* out = (float*)d_out;

    kAB_front<<<768, 256, 0, stream>>>(map_polylines, map_poly_mask,
        map_poly_type, map_tl_status, map_on_route,
        pm_w1, pm_b1, pm_w2, pm_b2, type_emb, tl_emb, route_emb,
        mo_w1, mo_b1, mo_w2, mo_b2,
        agents_state, agents_mask,
        ae_w1, ae_b1, ae_w2, ae_b2, ae_w3, ae_b3,
        map_node, map_nodeT, center, a_emb, aT, posT);

    kCD_fused<<<512, 512, 0, stream>>>(agents_state, agents_mask, map_poly_mask,
        a_emb, map_node, map_nodeT, center,
        mr_w1, mr_b1, mr_w2, mr_b2,
        aT, posT,
        nr_w1, nr_b1, nr_w2, nr_b2,
        to_w1, to_b1, to_w2, to_b2,
        out);
}